// Round 14
// baseline (194.186 us; speedup 1.0000x reference)
//
#include <hip/hip_runtime.h>

typedef unsigned short u16;
typedef unsigned int   u32;
typedef __attribute__((ext_vector_type(8))) short bf16x8;   // 8 bf16 = 4 VGPR (MFMA A/B frag)
typedef __attribute__((ext_vector_type(4))) float f32x4;    // MFMA C/D frag
typedef __attribute__((ext_vector_type(4))) u16   u16x4;

__device__ __forceinline__ u16 f2bf(float f) {              // RNE float->bf16
    u32 u = __float_as_uint(f);
    u32 r = (u + 0x7FFFu + ((u >> 16) & 1u)) >> 16;
    return (u16)r;
}
__device__ __forceinline__ float bf2f(u16 h) {
    return __uint_as_float(((u32)h) << 16);
}
// pack two f32 -> (bf16_b << 16) | bf16_a, RNE, PURE C++ (no inline asm!).
// v_exp_f32 is TRANS-pipe; its result must not be consumed by inline asm — the
// hazard recognizer cannot protect asm readers (R6/R8/R11/R12 failures; R13 proof).
__device__ __forceinline__ u32 pack2bf(float a, float b) {
    u32 ua = __float_as_uint(a), ub = __float_as_uint(b);
    u32 ra = (ua + 0x7FFFu + ((ua >> 16) & 1u)) >> 16;
    u32 rb = (ub + 0x7FFFu + ((ub >> 16) & 1u)) & 0xFFFF0000u;
    return ra | rb;
}
// single v_exp_f32 (TRANS pipe); consumers must be compiler-generated VALU only.
__device__ __forceinline__ float fexp2(float x) {
    return __builtin_amdgcn_exp2f(x);
}

// async global->LDS, 16B per lane. LDS dest is wave-uniform base (HW adds lane*16).
__device__ __forceinline__ void gll16(const u16* g, u16* l) {
    __builtin_amdgcn_global_load_lds(
        (const __attribute__((address_space(1))) u32*)(const void*)g,
        (__attribute__((address_space(3))) u32*)(void*)l, 16, 0, 0);
}

// ---------------- prep: fp32 -> bf16 (hi only) ----------------
__global__ void prep_hi(const float* __restrict__ src, u16* __restrict__ hi, int n4) {
    int i = blockIdx.x * blockDim.x + threadIdx.x;
    if (i >= n4) return;
    f32x4 v = *(const f32x4*)(src + (size_t)i * 4);
    u16x4 h;
#pragma unroll
    for (int j = 0; j < 4; j++) h[j] = f2bf(v[j]);
    *(u16x4*)(hi + (size_t)i * 4) = h;
}

// ---------------- prep: transpose (+ optional hi/lo split) weights -> Wt[N][K] -------
template<int WLO>
__global__ __launch_bounds__(256) void prep_wt(
    const float* __restrict__ Wq, const float* __restrict__ Wk, const float* __restrict__ Wv,
    u16* __restrict__ Whi, u16* __restrict__ Wlo, int K) {
    __shared__ float tile[32][33];
    int k0 = blockIdx.y * 32, n0 = blockIdx.x * 32;
    int tx = threadIdx.x & 31, ty = threadIdx.x >> 5;   // ty in 0..7
#pragma unroll
    for (int i = 0; i < 4; i++) {
        int kk = k0 + ty + i * 8;
        int n  = n0 + tx;
        float v;
        if (n < 1024)      v = Wq[(size_t)kk * 1024 + n];
        else if (n < 1280) v = Wk[(size_t)kk * 256 + (n - 1024)];
        else               v = Wv[(size_t)kk * 256 + (n - 1280)];
        tile[ty + i * 8][tx] = v;
    }
    __syncthreads();
#pragma unroll
    for (int i = 0; i < 4; i++) {
        int nn = n0 + ty + i * 8;      // output row (n)
        int kk = k0 + tx;              // output col (k)
        float v = tile[tx][ty + i * 8];
        u16 hh = f2bf(v);
        Whi[(size_t)nn * K + kk] = hh;
        if (WLO) Wlo[(size_t)nn * K + kk] = f2bf(v - bf2f(hh));
    }
}

__global__ void prep_bias(const float* __restrict__ bq, const float* __restrict__ bk,
                          const float* __restrict__ bv, float* __restrict__ out) {
    int i = blockIdx.x * blockDim.x + threadIdx.x;
    if (i >= 1536) return;
    out[i] = (i < 1024) ? bq[i] : ((i < 1280) ? bk[i - 1024] : bv[i - 1280]);
}

// ---------------- GEMM, 2-phase pipelined staging + chunk-XOR LDS swizzle -------------
// C[M][N] = A @ B^T (+ hi/lo split terms if TERMS==3) + bias.  Bt[N][K].
// Tile 128 x BN, 4 waves (2x2), each wave 64 x BN/2.  16x16x32 MFMA.
// MODE 0: write C fp32. MODE 1: fused QKV epilogue -> Qb(*0.125*log2e), Kb, Vb bf16.
template<int TERMS, int MODE, int BN>
__global__ __launch_bounds__(256) void gemm_2ph(
    const u16* __restrict__ Ahi, const u16* __restrict__ Alo,
    const u16* __restrict__ Bhi, const u16* __restrict__ Blo,
    const float* __restrict__ bias, float* __restrict__ C,
    u16* __restrict__ Qb, u16* __restrict__ Kb, u16* __restrict__ Vb,
    int M, int N, int K) {
    constexpr int NL = (TERMS == 3) ? 2 : 1;
    constexpr int NSUB = BN / 32;                       // 16-col subtiles per wave
    __shared__ __align__(16) u16 sA[2][NL][128 * 32];
    __shared__ __align__(16) u16 sB[2][NL][BN * 32];
    int tid = threadIdx.x;
    int lane = tid & 63;
    int wv = tid >> 6;
    int m0 = blockIdx.y * 128, n0 = blockIdx.x * BN;
    int wm = (wv >> 1) * 64, wn = (wv & 1) * (BN / 2);
    int lr = lane & 15, lg = lane >> 4;

    f32x4 acc[4][NSUB];
#pragma unroll
    for (int a = 0; a < 4; a++)
#pragma unroll
        for (int b = 0; b < NSUB; b++) acc[a][b] = (f32x4){0.f, 0.f, 0.f, 0.f};

    // staging geometry: waves cover rows 0..63 (A also +64); 4 chunks of 16B per row
    int rl = wv * 16 + (lane >> 2);
    int jl = (((lane & 3) ^ ((rl >> 1) & 3)) * 8);     // pre-swizzled source chunk
    size_t aoff = (size_t)(m0 + rl) * K + jl;
    size_t boff = (size_t)(n0 + rl) * K + jl;
    size_t rstep = (size_t)64 * K;

    auto STAGE = [&](int buf, int k0) {
#pragma unroll
        for (int lv = 0; lv < NL; lv++) {
            const u16* As = (lv == 0) ? Ahi : Alo;
            const u16* Bs = (lv == 0) ? Bhi : Blo;
            u16* dA = &sA[buf][lv][0] + wv * 512;
            u16* dB = &sB[buf][lv][0] + wv * 512;
            gll16(As + aoff + k0,         dA);
            gll16(As + aoff + rstep + k0, dA + 2048);
            gll16(Bs + boff + k0,         dB);
            if (BN == 128) gll16(Bs + boff + rstep + k0, dB + 2048);
        }
    };
    constexpr int LPS = NL * (3 + (BN == 128 ? 1 : 0));   // loads per stage per wave

    STAGE(0, 0);
    int nit = K >> 5;
    for (int it = 0; it < nit; ++it) {
        int cur = it & 1;
        if (it + 1 < nit) {
            STAGE(cur ^ 1, (it + 1) * 32);             // next tile in flight during compute
            asm volatile("s_waitcnt vmcnt(%0)" :: "n"(LPS) : "memory");
        } else {
            asm volatile("s_waitcnt vmcnt(0)" ::: "memory");
        }
        __builtin_amdgcn_s_barrier();
        asm volatile("" ::: "memory");

        bf16x8 af[NL][4], bfr[NL][NSUB];
#pragma unroll
        for (int ms = 0; ms < 4; ms++) {
            int row = wm + ms * 16 + lr;
            int off = row * 32 + (lg ^ ((row >> 1) & 3)) * 8;
#pragma unroll
            for (int lv = 0; lv < NL; lv++) af[lv][ms] = *(const bf16x8*)&sA[cur][lv][off];
        }
#pragma unroll
        for (int ns = 0; ns < NSUB; ns++) {
            int row = wn + ns * 16 + lr;
            int off = row * 32 + (lg ^ ((row >> 1) & 3)) * 8;
#pragma unroll
            for (int lv = 0; lv < NL; lv++) bfr[lv][ns] = *(const bf16x8*)&sB[cur][lv][off];
        }
#pragma unroll
        for (int ms = 0; ms < 4; ms++)
#pragma unroll
            for (int ns = 0; ns < NSUB; ns++) {
                f32x4 c = acc[ms][ns];
                c = __builtin_amdgcn_mfma_f32_16x16x32_bf16(af[0][ms], bfr[0][ns], c, 0, 0, 0);
                if constexpr (TERMS == 3) {
                    c = __builtin_amdgcn_mfma_f32_16x16x32_bf16(af[0][ms], bfr[1][ns], c, 0, 0, 0);
                    c = __builtin_amdgcn_mfma_f32_16x16x32_bf16(af[1][ms], bfr[0][ns], c, 0, 0, 0);
                }
                acc[ms][ns] = c;
            }
        __builtin_amdgcn_s_barrier();   // all reads of cur done before it is restaged
    }

    int rq = lg * 4;
#pragma unroll
    for (int ns = 0; ns < NSUB; ns++) {
        int n = n0 + wn + ns * 16 + lr;
        float bvv = bias[n];
#pragma unroll
        for (int ms = 0; ms < 4; ms++) {
            int mbase = m0 + wm + ms * 16 + rq;
#pragma unroll
            for (int r = 0; r < 4; r++) {
                float val = acc[ms][ns][r] + bvv;
                int m = mbase + r;
                if (MODE == 0) {
                    C[(size_t)m * N + n] = val;
                } else {
                    if (n < 1024)      Qb[(size_t)m * 1024 + n] = f2bf(val * 0.1803368801f);
                    else if (n < 1280) Kb[(size_t)m * 256 + (n - 1024)] = f2bf(val);
                    else               Vb[(size_t)m * 256 + (n - 1280)] = f2bf(val);
                }
            }
        }
    }
}

// ---------------- prep: Vb bf16 -> V^T per (b,g), key-PERMUTED within 64-blocks -------
// position p within a 64-token block holds token ti = ((p&1)<<4) | ((p>>1)&15) | (p&32)
// (so positions 2i/2i+1 = tokens i/16+i) matching the P-pack layout in attn.
__global__ __launch_bounds__(256) void prep_vt(const u16* __restrict__ Vb,
                                               u16* __restrict__ Vtp) {
    int blk = blockIdx.x;                 // 2*4*32
    int tk = blk & 31, gg = (blk >> 5) & 3, bb = blk >> 7;
    int tok0 = tk * 64;
    __shared__ u16 lt[64][72];
    int t = threadIdx.x;
#pragma unroll
    for (int i = 0; i < 16; i++) {
        int idx = t + i * 256;
        int ti = idx >> 6, dh = idx & 63;
        lt[dh][ti] = Vb[(size_t)(bb * 2048 + tok0 + ti) * 256 + gg * 64 + dh];
    }
    __syncthreads();
#pragma unroll
    for (int i = 0; i < 16; i++) {
        int idx = t + i * 256;
        int dh = idx >> 6, p = idx & 63;
        int ti = ((p & 1) << 4) | ((p >> 1) & 15) | (p & 32);
        Vtp[(size_t)((bb * 4 + gg) * 64 + dh) * 2048 + tok0 + p] = lt[dh][ti];
    }
}

// ---------------- flash attention: 4-way KV-split, 4 waves/block, K/V from L2 --------
// R13-proven base (builtin exp2 + pure-C++ pack). Single change vs R13: V register
// double-buffer — prefetch tile it+1 at the TOP of iter it into the buffer last read
// by PV of it-1 (a full iteration retired; no in-flight MFMA reads it), latency
// hidden under QK+exp2/pack. (R12 proved load motion was NOT the R8/R11 culprit.)
__global__ __launch_bounds__(256) void attn_kernel(
    const u16* __restrict__ Qb, const u16* __restrict__ Kb,
    const u16* __restrict__ Vtp, u16* __restrict__ Ohi, u16* __restrict__ Olo) {
    __shared__ __align__(16) char smem[40960];

    const int tid = threadIdx.x;
    const int wv = tid >> 6, lane = tid & 63;
    const int lr = lane & 15, lg = lane >> 4;
    const int bid = blockIdx.x;
    const int g  = bid & 3;                  // bid&7 = (b,g) -> XCD-local K/V stream
    const int b  = (bid >> 2) & 1;
    const int h  = g * 4 + ((bid >> 3) & 3);
    const int qc = (bid >> 5) & 31;
    const int tok0 = qc * 64;

    u16* sPw = (u16*)(smem + wv * 9216);

    // Q A-fragments: 4 m-tiles x 2 k-steps (row = lane&15, k = lg*8+j)
    bf16x8 qf[4][2];
#pragma unroll
    for (int mm = 0; mm < 4; mm++) {
        const u16* qrow = Qb + (size_t)(b * 2048 + tok0 + mm * 16 + lr) * 1024 + h * 64 + lg * 8;
        qf[mm][0] = *(const bf16x8*)(qrow);
        qf[mm][1] = *(const bf16x8*)(qrow + 32);
    }

    const u16* kb_ = Kb + (size_t)(b * 2048 + wv * 512) * 256 + g * 64 + lg * 8;  // +key*256
    const u16* vb_ = Vtp + (size_t)((b * 4 + g) * 64) * 2048 + wv * 512 + lg * 8; // +dh*2048+tok

    f32x4 o_[4][4];
    float ls[4][4];
#pragma unroll
    for (int mm = 0; mm < 4; mm++)
#pragma unroll
        for (int r = 0; r < 4; r++) { o_[mm][r] = (f32x4){0.f, 0.f, 0.f, 0.f}; ls[mm][r] = 0.f; }

    // prefetch K tile 0; V tile 0 into buffer 0
    bf16x8 kf0[4], kf1[4], vfA[2][4], vfB[2][4];
#pragma unroll
    for (int t = 0; t < 4; t++) {
        const u16* kr = kb_ + (size_t)(t * 16 + lr) * 256;
        kf0[t] = *(const bf16x8*)(kr);
        kf1[t] = *(const bf16x8*)(kr + 32);
    }
#pragma unroll
    for (int ks = 0; ks < 2; ks++)
#pragma unroll
        for (int n = 0; n < 4; n++)
            vfA[ks][n] = *(const bf16x8*)(vb_ + (size_t)(n * 16 + lr) * 2048 + ks * 32);

    for (int it = 0; it < 8; ++it) {
        const bool even = (it & 1) == 0;
        // ---- prefetch V for NEXT tile into the other buffer (its last reader was
        //      PV of it-1, fully retired); latency hides under QK+exp2/pack ----
        if (it < 7) {
#pragma unroll
            for (int ks = 0; ks < 2; ks++)
#pragma unroll
                for (int n = 0; n < 4; n++) {
                    bf16x8 v = *(const bf16x8*)(vb_ + (size_t)(n * 16 + lr) * 2048 + (it + 1) * 64 + ks * 32);
                    if (even) vfB[ks][n] = v; else vfA[ks][n] = v;
                }
        }
        // ---- per m-tile: QK^T then exp2/pack (keeps s live-range at 16 regs) ----
#pragma unroll
        for (int mm = 0; mm < 4; mm++) {
            f32x4 s[4];
#pragma unroll
            for (int t = 0; t < 4; t++) {
                f32x4 sc = (f32x4){0.f, 0.f, 0.f, 0.f};
                sc = __builtin_amdgcn_mfma_f32_16x16x32_bf16(qf[mm][0], kf0[t], sc, 0, 0, 0);
                sc = __builtin_amdgcn_mfma_f32_16x16x32_bf16(qf[mm][1], kf1[t], sc, 0, 0, 0);
                s[t] = sc;
            }
#pragma unroll
            for (int r = 0; r < 4; r++) {
                float p0 = fexp2(s[0][r]);
                float p1 = fexp2(s[1][r]);
                float p2 = fexp2(s[2][r]);
                float p3 = fexp2(s[3][r]);
                ls[mm][r] += (p0 + p1) + (p2 + p3);
                u32 w0 = pack2bf(p0, p1);        // slots 2lr,2lr+1  = keys lr,16+lr
                u32 w1 = pack2bf(p2, p3);        // slots 32+2lr,..  = keys 32+lr,48+lr
                int rowo = (mm * 16 + lg * 4 + r) * 72;
                *(u32*)(sPw + rowo + lr * 2)      = w0;
                *(u32*)(sPw + rowo + 32 + lr * 2) = w1;
            }
        }
        // ---- refill K fragments for next tile (consumed next iteration) ----
        if (it < 7) {
            const u16* kn = kb_ + (size_t)(it + 1) * 16384;
#pragma unroll
            for (int t = 0; t < 4; t++) {
                const u16* kr = kn + (size_t)(t * 16 + lr) * 256;
                kf0[t] = *(const bf16x8*)(kr);
                kf1[t] = *(const bf16x8*)(kr + 32);
            }
        }
        asm volatile("s_waitcnt lgkmcnt(0)" ::: "memory");
        __builtin_amdgcn_sched_barrier(0);
        // ---- O += P @ V (V key-permuted to match P slots; current buffer) ----
#pragma unroll
        for (int ks = 0; ks < 2; ks++)
#pragma unroll
            for (int mm = 0; mm < 4; mm++) {
                bf16x8 pa = *(const bf16x8*)(sPw + (mm * 16 + lr) * 72 + ks * 32 + lg * 8);
#pragma unroll
                for (int n = 0; n < 4; n++) {
                    bf16x8 vf = even ? vfA[ks][n] : vfB[ks][n];
                    o_[mm][n] = __builtin_amdgcn_mfma_f32_16x16x32_bf16(pa, vf, o_[mm][n], 0, 0, 0);
                }
            }
    }

    // ---- combine across waves: 2-stage tree (1->0, 3->2 in parallel, then 2->0) ----
    auto dumpO = [&](float* qreg, float* lreg) {
#pragma unroll
        for (int mm = 0; mm < 4; mm++)
#pragma unroll
            for (int n = 0; n < 4; n++)
#pragma unroll
                for (int r = 0; r < 4; r++)
                    qreg[(mm * 16 + lg * 4 + r) * 64 + n * 16 + lr] = o_[mm][n][r];
#pragma unroll
        for (int mm = 0; mm < 4; mm++)
#pragma unroll
            for (int r = 0; r < 4; r++) lreg[(mm * 4 + r) * 64 + lane] = ls[mm][r];
    };
    auto absorbO = [&](float* qreg, float* lreg) {
#pragma unroll
        for (int mm = 0; mm < 4; mm++)
#pragma unroll
            for (int n = 0; n < 4; n++)
#pragma unroll
                for (int r = 0; r < 4; r++)
                    o_[mm][n][r] += qreg[(mm * 16 + lg * 4 + r) * 64 + n * 16 + lr];
#pragma unroll
        for (int mm = 0; mm < 4; mm++)
#pragma unroll
            for (int r = 0; r < 4; r++) ls[mm][r] += lreg[(mm * 4 + r) * 64 + lane];
    };

    float* reg0q = (float*)smem;                    // region 0: [0, 20480)
    float* reg0l = reg0q + 4096;
    float* reg1q = (float*)(smem + 20480);          // region 1: [20480, 40960)
    float* reg1l = reg1q + 4096;

    __syncthreads();
    if (wv == 1) dumpO(reg0q, reg0l);
    if (wv == 3) dumpO(reg1q, reg1l);
    __syncthreads();
    if (wv == 0) absorbO(reg0q, reg0l);
    if (wv == 2) absorbO(reg1q, reg1l);
    __syncthreads();
    if (wv == 2) dumpO(reg0q, reg0l);
    __syncthreads();
    if (wv == 0) {
        absorbO(reg0q, reg0l);
#pragma unroll
        for (int mm = 0; mm < 4; mm++)
#pragma unroll
            for (int r = 0; r < 4; r++) {
                float l = ls[mm][r];
#pragma unroll
                for (int off = 1; off < 16; off <<= 1) l += __shfl_xor(l, off, 64);
                float inv = 1.f / l;
                int row = b * 2048 + tok0 + mm * 16 + lg * 4 + r;
#pragma unroll
                for (int n = 0; n < 4; n++) {
                    float val = o_[mm][n][r] * inv;
                    u16 hh = f2bf(val);
                    size_t idx = (size_t)row * 1024 + h * 64 + n * 16 + lr;
                    Ohi[idx] = hh;
                    Olo[idx] = f2bf(val - bf2f(hh));
                }
            }
    }
}

// ---------------- launch ----------------
extern "C" void kernel_launch(void* const* d_in, const int* in_sizes, int n_in,
                              void* d_out, int out_size, void* d_ws, size_t ws_size,
                              hipStream_t stream) {
    const float* x   = (const float*)d_in[0];
    const float* W_q = (const float*)d_in[1];
    const float* b_q = (const float*)d_in[2];
    const float* W_k = (const float*)d_in[3];
    const float* b_k = (const float*)d_in[4];
    const float* W_v = (const float*)d_in[5];
    const float* b_v = (const float*)d_in[6];
    const float* W_o = (const float*)d_in[7];
    const float* b_o = (const float*)d_in[8];
    float* out = (float*)d_out;

    char* ws = (char*)d_ws;
    u16*   xhi   = (u16*)(ws + 0);            //  8 MB  [4096][1024]
    u16*   Wqkvh = (u16*)(ws + 8388608);      //  3 MB  [1536][1024]
    float* bqkv  = (float*)(ws + 11534336);   //  6 KB
    u16*   Qb    = (u16*)(ws + 11540480);     //  8 MB  [4096][1024] (pre-scaled)
    u16*   Kb    = (u16*)(ws + 19929088);     //  2 MB  [4096][256]
    u16*   Vb    = (u16*)(ws + 22026240);     //  2 MB  [4096][256]
    u16*   Vtp   = (u16*)(ws + 24123392);     //  2 MB  [8][64][2048] key-permuted
    u16*   Woh   = (u16*)(ws + 26220544);     //  2 MB  [1024][1024]
    u16*   Wol   = (u16*)(ws + 28317696);     //  2 MB
    u16*   Ahi   = (u16*)(ws + 30414848);     //  8 MB  attn-out hi
    u16*   Alo   = (u16*)(ws + 38803456);     //  8 MB  attn-out lo (ends 47,192,064)

    prep_hi<<<4096, 256, 0, stream>>>(x, xhi, 4096 * 1024 / 4);
    prep_wt<0><<<dim3(48, 32), 256, 0, stream>>>(W_q, W_k, W_v, Wqkvh, nullptr, 1024);
    prep_wt<1><<<dim3(32, 32), 256, 0, stream>>>(W_o, W_o, W_o, Woh, Wol, 1024);
    prep_bias<<<6, 256, 0, stream>>>(b_q, b_k, b_v, bqkv);
    gemm_2ph<1, 1, 64><<<dim3(24, 32), 256, 0, stream>>>(xhi, nullptr, Wqkvh, nullptr, bqkv,
                                                         nullptr, Qb, Kb, Vb, 4096, 1536, 1024);
    prep_vt<<<256, 256, 0, stream>>>(Vb, Vtp);
    attn_kernel<<<1024, 256, 0, stream>>>(Qb, Kb, Vtp, Ahi, Alo);
    gemm_2ph<3, 0, 64><<<dim3(16, 32), 256, 0, stream>>>(Ahi, Alo, Woh, Wol, b_o, out,
                                                         nullptr, nullptr, nullptr, 4096, 1024, 1024);
}

// Round 15
// 159.252 us; speedup vs baseline: 1.2194x; 1.2194x over previous
//
#include <hip/hip_runtime.h>

typedef unsigned short u16;
typedef unsigned int   u32;
typedef __attribute__((ext_vector_type(8))) short bf16x8;   // 8 bf16 = 4 VGPR (MFMA A/B frag)
typedef __attribute__((ext_vector_type(4))) float f32x4;    // MFMA C/D frag
typedef __attribute__((ext_vector_type(4))) u16   u16x4;

__device__ __forceinline__ u16 f2bf(float f) {              // RNE float->bf16
    u32 u = __float_as_uint(f);
    u32 r = (u + 0x7FFFu + ((u >> 16) & 1u)) >> 16;
    return (u16)r;
}
__device__ __forceinline__ float bf2f(u16 h) {
    return __uint_as_float(((u32)h) << 16);
}
// pack two f32 -> (bf16_b << 16) | bf16_a, RNE, PURE C++ (no inline asm!).
// v_exp_f32 is TRANS-pipe; its result must not be consumed by inline asm — the
// hazard recognizer cannot protect asm readers (R6/R8/R11/R12 failures; R13 proof).
__device__ __forceinline__ u32 pack2bf(float a, float b) {
    u32 ua = __float_as_uint(a), ub = __float_as_uint(b);
    u32 ra = (ua + 0x7FFFu + ((ua >> 16) & 1u)) >> 16;
    u32 rb = (ub + 0x7FFFu + ((ub >> 16) & 1u)) & 0xFFFF0000u;
    return ra | rb;
}
// single v_exp_f32 (TRANS pipe); consumers must be compiler-generated VALU only.
__device__ __forceinline__ float fexp2(float x) {
    return __builtin_amdgcn_exp2f(x);
}

// async global->LDS, 16B per lane. LDS dest is wave-uniform base (HW adds lane*16).
__device__ __forceinline__ void gll16(const u16* g, u16* l) {
    __builtin_amdgcn_global_load_lds(
        (const __attribute__((address_space(1))) u32*)(const void*)g,
        (__attribute__((address_space(3))) u32*)(void*)l, 16, 0, 0);
}

// ---------------- prep: fp32 -> bf16 (hi only) ----------------
__global__ void prep_hi(const float* __restrict__ src, u16* __restrict__ hi, int n4) {
    int i = blockIdx.x * blockDim.x + threadIdx.x;
    if (i >= n4) return;
    f32x4 v = *(const f32x4*)(src + (size_t)i * 4);
    u16x4 h;
#pragma unroll
    for (int j = 0; j < 4; j++) h[j] = f2bf(v[j]);
    *(u16x4*)(hi + (size_t)i * 4) = h;
}

// ---------------- prep: transpose (+ optional hi/lo split) weights -> Wt[N][K] -------
template<int WLO>
__global__ __launch_bounds__(256) void prep_wt(
    const float* __restrict__ Wq, const float* __restrict__ Wk, const float* __restrict__ Wv,
    u16* __restrict__ Whi, u16* __restrict__ Wlo, int K) {
    __shared__ float tile[32][33];
    int k0 = blockIdx.y * 32, n0 = blockIdx.x * 32;
    int tx = threadIdx.x & 31, ty = threadIdx.x >> 5;   // ty in 0..7
#pragma unroll
    for (int i = 0; i < 4; i++) {
        int kk = k0 + ty + i * 8;
        int n  = n0 + tx;
        float v;
        if (n < 1024)      v = Wq[(size_t)kk * 1024 + n];
        else if (n < 1280) v = Wk[(size_t)kk * 256 + (n - 1024)];
        else               v = Wv[(size_t)kk * 256 + (n - 1280)];
        tile[ty + i * 8][tx] = v;
    }
    __syncthreads();
#pragma unroll
    for (int i = 0; i < 4; i++) {
        int nn = n0 + ty + i * 8;      // output row (n)
        int kk = k0 + tx;              // output col (k)
        float v = tile[tx][ty + i * 8];
        u16 hh = f2bf(v);
        Whi[(size_t)nn * K + kk] = hh;
        if (WLO) Wlo[(size_t)nn * K + kk] = f2bf(v - bf2f(hh));
    }
}

__global__ void prep_bias(const float* __restrict__ bq, const float* __restrict__ bk,
                          const float* __restrict__ bv, float* __restrict__ out) {
    int i = blockIdx.x * blockDim.x + threadIdx.x;
    if (i >= 1536) return;
    out[i] = (i < 1024) ? bq[i] : ((i < 1280) ? bk[i - 1024] : bv[i - 1280]);
}

// ---------------- GEMM, 2-phase pipelined staging + chunk-XOR LDS swizzle -------------
// C[M][N] = A @ B^T (+ hi/lo split terms if TERMS==3) + bias.  Bt[N][K].
// Tile 128 x BN, 4 waves (2x2), each wave 64 x BN/2.  16x16x32 MFMA.
// MODE 0: write C fp32. MODE 1: fused QKV epilogue -> Qb(*0.125*log2e), Kb, Vb bf16.
template<int TERMS, int MODE, int BN>
__global__ __launch_bounds__(256) void gemm_2ph(
    const u16* __restrict__ Ahi, const u16* __restrict__ Alo,
    const u16* __restrict__ Bhi, const u16* __restrict__ Blo,
    const float* __restrict__ bias, float* __restrict__ C,
    u16* __restrict__ Qb, u16* __restrict__ Kb, u16* __restrict__ Vb,
    int M, int N, int K) {
    constexpr int NL = (TERMS == 3) ? 2 : 1;
    constexpr int NSUB = BN / 32;                       // 16-col subtiles per wave
    __shared__ __align__(16) u16 sA[2][NL][128 * 32];
    __shared__ __align__(16) u16 sB[2][NL][BN * 32];
    int tid = threadIdx.x;
    int lane = tid & 63;
    int wv = tid >> 6;
    int m0 = blockIdx.y * 128, n0 = blockIdx.x * BN;
    int wm = (wv >> 1) * 64, wn = (wv & 1) * (BN / 2);
    int lr = lane & 15, lg = lane >> 4;

    f32x4 acc[4][NSUB];
#pragma unroll
    for (int a = 0; a < 4; a++)
#pragma unroll
        for (int b = 0; b < NSUB; b++) acc[a][b] = (f32x4){0.f, 0.f, 0.f, 0.f};

    // staging geometry: waves cover rows 0..63 (A also +64); 4 chunks of 16B per row
    int rl = wv * 16 + (lane >> 2);
    int jl = (((lane & 3) ^ ((rl >> 1) & 3)) * 8);     // pre-swizzled source chunk
    size_t aoff = (size_t)(m0 + rl) * K + jl;
    size_t boff = (size_t)(n0 + rl) * K + jl;
    size_t rstep = (size_t)64 * K;

    auto STAGE = [&](int buf, int k0) {
#pragma unroll
        for (int lv = 0; lv < NL; lv++) {
            const u16* As = (lv == 0) ? Ahi : Alo;
            const u16* Bs = (lv == 0) ? Bhi : Blo;
            u16* dA = &sA[buf][lv][0] + wv * 512;
            u16* dB = &sB[buf][lv][0] + wv * 512;
            gll16(As + aoff + k0,         dA);
            gll16(As + aoff + rstep + k0, dA + 2048);
            gll16(Bs + boff + k0,         dB);
            if (BN == 128) gll16(Bs + boff + rstep + k0, dB + 2048);
        }
    };
    constexpr int LPS = NL * (3 + (BN == 128 ? 1 : 0));   // loads per stage per wave

    STAGE(0, 0);
    int nit = K >> 5;
    for (int it = 0; it < nit; ++it) {
        int cur = it & 1;
        if (it + 1 < nit) {
            STAGE(cur ^ 1, (it + 1) * 32);             // next tile in flight during compute
            asm volatile("s_waitcnt vmcnt(%0)" :: "n"(LPS) : "memory");
        } else {
            asm volatile("s_waitcnt vmcnt(0)" ::: "memory");
        }
        __builtin_amdgcn_s_barrier();
        asm volatile("" ::: "memory");

        bf16x8 af[NL][4], bfr[NL][NSUB];
#pragma unroll
        for (int ms = 0; ms < 4; ms++) {
            int row = wm + ms * 16 + lr;
            int off = row * 32 + (lg ^ ((row >> 1) & 3)) * 8;
#pragma unroll
            for (int lv = 0; lv < NL; lv++) af[lv][ms] = *(const bf16x8*)&sA[cur][lv][off];
        }
#pragma unroll
        for (int ns = 0; ns < NSUB; ns++) {
            int row = wn + ns * 16 + lr;
            int off = row * 32 + (lg ^ ((row >> 1) & 3)) * 8;
#pragma unroll
            for (int lv = 0; lv < NL; lv++) bfr[lv][ns] = *(const bf16x8*)&sB[cur][lv][off];
        }
#pragma unroll
        for (int ms = 0; ms < 4; ms++)
#pragma unroll
            for (int ns = 0; ns < NSUB; ns++) {
                f32x4 c = acc[ms][ns];
                c = __builtin_amdgcn_mfma_f32_16x16x32_bf16(af[0][ms], bfr[0][ns], c, 0, 0, 0);
                if constexpr (TERMS == 3) {
                    c = __builtin_amdgcn_mfma_f32_16x16x32_bf16(af[0][ms], bfr[1][ns], c, 0, 0, 0);
                    c = __builtin_amdgcn_mfma_f32_16x16x32_bf16(af[1][ms], bfr[0][ns], c, 0, 0, 0);
                }
                acc[ms][ns] = c;
            }
        __builtin_amdgcn_s_barrier();   // all reads of cur done before it is restaged
    }

    int rq = lg * 4;
#pragma unroll
    for (int ns = 0; ns < NSUB; ns++) {
        int n = n0 + wn + ns * 16 + lr;
        float bvv = bias[n];
#pragma unroll
        for (int ms = 0; ms < 4; ms++) {
            int mbase = m0 + wm + ms * 16 + rq;
#pragma unroll
            for (int r = 0; r < 4; r++) {
                float val = acc[ms][ns][r] + bvv;
                int m = mbase + r;
                if (MODE == 0) {
                    C[(size_t)m * N + n] = val;
                } else {
                    if (n < 1024)      Qb[(size_t)m * 1024 + n] = f2bf(val * 0.1803368801f);
                    else if (n < 1280) Kb[(size_t)m * 256 + (n - 1024)] = f2bf(val);
                    else               Vb[(size_t)m * 256 + (n - 1280)] = f2bf(val);
                }
            }
        }
    }
}

// ---------------- prep: Vb bf16 -> V^T per (b,g), key-PERMUTED within 64-blocks -------
// position p within a 64-token block holds token ti = ((p&1)<<4) | ((p>>1)&15) | (p&32)
// (so positions 2i/2i+1 = tokens i/16+i) matching the P-pack layout in attn.
__global__ __launch_bounds__(256) void prep_vt(const u16* __restrict__ Vb,
                                               u16* __restrict__ Vtp) {
    int blk = blockIdx.x;                 // 2*4*32
    int tk = blk & 31, gg = (blk >> 5) & 3, bb = blk >> 7;
    int tok0 = tk * 64;
    __shared__ u16 lt[64][72];
    int t = threadIdx.x;
#pragma unroll
    for (int i = 0; i < 16; i++) {
        int idx = t + i * 256;
        int ti = idx >> 6, dh = idx & 63;
        lt[dh][ti] = Vb[(size_t)(bb * 2048 + tok0 + ti) * 256 + gg * 64 + dh];
    }
    __syncthreads();
#pragma unroll
    for (int i = 0; i < 16; i++) {
        int idx = t + i * 256;
        int dh = idx >> 6, p = idx & 63;
        int ti = ((p & 1) << 4) | ((p >> 1) & 15) | (p & 32);
        Vtp[(size_t)((bb * 4 + gg) * 64 + dh) * 2048 + tok0 + p] = lt[dh][ti];
    }
}

// ---------------- flash attention: 4-way KV-split, 4 waves/block, K/V from L2 --------
// R13-proven loop (byte-identical). Single change: LDS 40960 -> 36864 (sP only;
// combine serialized through ONE 20480B region overlaid on sP, as in R7). 4 x 36864
// = 147456 <= 160KB minus runtime reserve -> true 4 blocks/CU in ONE generation
// (40960 x 4 = exactly 163840 left zero margin; occupancy was stuck at ~18%).
__global__ __launch_bounds__(256) void attn_kernel(
    const u16* __restrict__ Qb, const u16* __restrict__ Kb,
    const u16* __restrict__ Vtp, u16* __restrict__ Ohi, u16* __restrict__ Olo) {
    __shared__ __align__(16) char smem[36864];

    const int tid = threadIdx.x;
    const int wv = tid >> 6, lane = tid & 63;
    const int lr = lane & 15, lg = lane >> 4;
    const int bid = blockIdx.x;
    const int g  = bid & 3;                  // bid&7 = (b,g) -> XCD-local K/V stream
    const int b  = (bid >> 2) & 1;
    const int h  = g * 4 + ((bid >> 3) & 3);
    const int qc = (bid >> 5) & 31;
    const int tok0 = qc * 64;

    u16* sPw = (u16*)(smem + wv * 9216);

    // Q A-fragments: 4 m-tiles x 2 k-steps (row = lane&15, k = lg*8+j)
    bf16x8 qf[4][2];
#pragma unroll
    for (int mm = 0; mm < 4; mm++) {
        const u16* qrow = Qb + (size_t)(b * 2048 + tok0 + mm * 16 + lr) * 1024 + h * 64 + lg * 8;
        qf[mm][0] = *(const bf16x8*)(qrow);
        qf[mm][1] = *(const bf16x8*)(qrow + 32);
    }

    const u16* kb_ = Kb + (size_t)(b * 2048 + wv * 512) * 256 + g * 64 + lg * 8;  // +key*256
    const u16* vb_ = Vtp + (size_t)((b * 4 + g) * 64) * 2048 + wv * 512 + lg * 8; // +dh*2048+tok

    f32x4 o_[4][4];
    float ls[4][4];
#pragma unroll
    for (int mm = 0; mm < 4; mm++)
#pragma unroll
        for (int r = 0; r < 4; r++) { o_[mm][r] = (f32x4){0.f, 0.f, 0.f, 0.f}; ls[mm][r] = 0.f; }

    // prefetch K tile 0
    bf16x8 kf0[4], kf1[4];
#pragma unroll
    for (int t = 0; t < 4; t++) {
        const u16* kr = kb_ + (size_t)(t * 16 + lr) * 256;
        kf0[t] = *(const bf16x8*)(kr);
        kf1[t] = *(const bf16x8*)(kr + 32);
    }

    for (int it = 0; it < 8; ++it) {
        // ---- per m-tile: QK^T then exp2/pack (keeps s live-range at 16 regs) ----
#pragma unroll
        for (int mm = 0; mm < 4; mm++) {
            f32x4 s[4];
#pragma unroll
            for (int t = 0; t < 4; t++) {
                f32x4 sc = (f32x4){0.f, 0.f, 0.f, 0.f};
                sc = __builtin_amdgcn_mfma_f32_16x16x32_bf16(qf[mm][0], kf0[t], sc, 0, 0, 0);
                sc = __builtin_amdgcn_mfma_f32_16x16x32_bf16(qf[mm][1], kf1[t], sc, 0, 0, 0);
                s[t] = sc;
            }
#pragma unroll
            for (int r = 0; r < 4; r++) {
                float p0 = fexp2(s[0][r]);
                float p1 = fexp2(s[1][r]);
                float p2 = fexp2(s[2][r]);
                float p3 = fexp2(s[3][r]);
                ls[mm][r] += (p0 + p1) + (p2 + p3);
                u32 w0 = pack2bf(p0, p1);        // slots 2lr,2lr+1  = keys lr,16+lr
                u32 w1 = pack2bf(p2, p3);        // slots 32+2lr,..  = keys 32+lr,48+lr
                int rowo = (mm * 16 + lg * 4 + r) * 72;
                *(u32*)(sPw + rowo + lr * 2)      = w0;
                *(u32*)(sPw + rowo + 32 + lr * 2) = w1;
            }
        }
        // ---- refill K fragments for next tile (consumed next iteration) ----
        if (it < 7) {
            const u16* kn = kb_ + (size_t)(it + 1) * 16384;
#pragma unroll
            for (int t = 0; t < 4; t++) {
                const u16* kr = kn + (size_t)(t * 16 + lr) * 256;
                kf0[t] = *(const bf16x8*)(kr);
                kf1[t] = *(const bf16x8*)(kr + 32);
            }
        }
        // ---- V fragments for this tile ----
        bf16x8 vf[2][4];
#pragma unroll
        for (int ks = 0; ks < 2; ks++)
#pragma unroll
            for (int n = 0; n < 4; n++)
                vf[ks][n] = *(const bf16x8*)(vb_ + (size_t)(n * 16 + lr) * 2048 + it * 64 + ks * 32);
        asm volatile("s_waitcnt lgkmcnt(0)" ::: "memory");
        __builtin_amdgcn_sched_barrier(0);
        // ---- O += P @ V (V key-permuted to match P slots) ----
#pragma unroll
        for (int ks = 0; ks < 2; ks++)
#pragma unroll
            for (int mm = 0; mm < 4; mm++) {
                bf16x8 pa = *(const bf16x8*)(sPw + (mm * 16 + lr) * 72 + ks * 32 + lg * 8);
#pragma unroll
                for (int n = 0; n < 4; n++)
                    o_[mm][n] = __builtin_amdgcn_mfma_f32_16x16x32_bf16(pa, vf[ks][n], o_[mm][n], 0, 0, 0);
            }
    }

    // ---- combine across waves, fully serialized through ONE region on sP ----
    float* qreg = (float*)smem;          // O partials: [64 q][64] f32 = 16384B
    float* lreg = qreg + 4096;           // ls partials: [16][64] f32 = 4096B (ends 20480)
    auto dumpO = [&]() {
#pragma unroll
        for (int mm = 0; mm < 4; mm++)
#pragma unroll
            for (int n = 0; n < 4; n++)
#pragma unroll
                for (int r = 0; r < 4; r++)
                    qreg[(mm * 16 + lg * 4 + r) * 64 + n * 16 + lr] = o_[mm][n][r];
#pragma unroll
        for (int mm = 0; mm < 4; mm++)
#pragma unroll
            for (int r = 0; r < 4; r++) lreg[(mm * 4 + r) * 64 + lane] = ls[mm][r];
    };
    auto absorbO = [&]() {
#pragma unroll
        for (int mm = 0; mm < 4; mm++)
#pragma unroll
            for (int n = 0; n < 4; n++)
#pragma unroll
                for (int r = 0; r < 4; r++)
                    o_[mm][n][r] += qreg[(mm * 16 + lg * 4 + r) * 64 + n * 16 + lr];
#pragma unroll
        for (int mm = 0; mm < 4; mm++)
#pragma unroll
            for (int r = 0; r < 4; r++) ls[mm][r] += lreg[(mm * 4 + r) * 64 + lane];
    };

    __syncthreads();
    if (wv == 1) dumpO();
    __syncthreads();
    if (wv == 0) absorbO();
    __syncthreads();
    if (wv == 3) dumpO();
    __syncthreads();
    if (wv == 2) absorbO();
    __syncthreads();
    if (wv == 2) dumpO();
    __syncthreads();
    if (wv == 0) {
        absorbO();
#pragma unroll
        for (int mm = 0; mm < 4; mm++)
#pragma unroll
            for (int r = 0; r < 4; r++) {
                float l = ls[mm][r];
#pragma unroll
                for (int off = 1; off < 16; off <<= 1) l += __shfl_xor(l, off, 64);
                float inv = 1.f / l;
                int row = b * 2048 + tok0 + mm * 16 + lg * 4 + r;
#pragma unroll
                for (int n = 0; n < 4; n++) {
                    float val = o_[mm][n][r] * inv;
                    u16 hh = f2bf(val);
                    size_t idx = (size_t)row * 1024 + h * 64 + n * 16 + lr;
                    Ohi[idx] = hh;
                    Olo[idx] = f2bf(val - bf2f(hh));
                }
            }
    }
}

// ---------------- launch ----------------
extern "C" void kernel_launch(void* const* d_in, const int* in_sizes, int n_in,
                              void* d_out, int out_size, void* d_ws, size_t ws_size,
                              hipStream_t stream) {
    const float* x   = (const float*)d_in[0];
    const float* W_q = (const float*)d_in[1];
    const float* b_q = (const float*)d_in[2];
    const float* W_k = (const float*)d_in[3];
    const float* b_k = (const float*)d_in[4];
    const float* W_v = (const float*)d_in[5];
    const float* b_v = (const float*)d_in[6];
    const float* W_o = (const float*)d_in[7];
    const float* b_o = (const float*)d_in[8];
    float* out = (float*)d_out;

    char* ws = (char*)d_ws;
    u16*   xhi   = (u16*)(ws + 0);            //  8 MB  [4096][1024]
    u16*   Wqkvh = (u16*)(ws + 8388608);      //  3 MB  [1536][1024]
    float* bqkv  = (float*)(ws + 11534336);   //  6 KB
    u16*   Qb    = (u16*)(ws + 11540480);     //  8 MB  [4096][1024] (pre-scaled)
    u16*   Kb    = (u16*)(ws + 19929088);     //  2 MB  [4096][256]
    u16*   Vb    = (u16*)(ws + 22026240);     //  2 MB  [4096][256]
    u16*   Vtp   = (u16*)(ws + 24123392);     //  2 MB  [8][64][2048] key-permuted
    u16*   Woh   = (u16*)(ws + 26220544);     //  2 MB  [1024][1024]
    u16*   Wol   = (u16*)(ws + 28317696);     //  2 MB
    u16*   Ahi   = (u16*)(ws + 30414848);     //  8 MB  attn-out hi
    u16*   Alo   = (u16*)(ws + 38803456);     //  8 MB  attn-out lo (ends 47,192,064)

    prep_hi<<<4096, 256, 0, stream>>>(x, xhi, 4096 * 1024 / 4);
    prep_wt<0><<<dim3(48, 32), 256, 0, stream>>>(W_q, W_k, W_v, Wqkvh, nullptr, 1024);
    prep_wt<1><<<dim3(32, 32), 256, 0, stream>>>(W_o, W_o, W_o, Woh, Wol, 1024);
    prep_bias<<<6, 256, 0, stream>>>(b_q, b_k, b_v, bqkv);
    gemm_2ph<1, 1, 64><<<dim3(24, 32), 256, 0, stream>>>(xhi, nullptr, Wqkvh, nullptr, bqkv,
                                                         nullptr, Qb, Kb, Vb, 4096, 1536, 1024);
    prep_vt<<<256, 256, 0, stream>>>(Vb, Vtp);
    attn_kernel<<<1024, 256, 0, stream>>>(Qb, Kb, Vtp, Ahi, Alo);
    gemm_2ph<3, 0, 64><<<dim3(16, 32), 256, 0, stream>>>(Ahi, Alo, Woh, Wol, b_o, out,
                                                         nullptr, nullptr, nullptr, 4096, 1024, 1024);
}

// Round 16
// 143.186 us; speedup vs baseline: 1.3562x; 1.1122x over previous
//
#include <hip/hip_runtime.h>

typedef unsigned short u16;
typedef unsigned int   u32;
typedef __attribute__((ext_vector_type(8))) short bf16x8;   // 8 bf16 = 4 VGPR (MFMA A/B frag)
typedef __attribute__((ext_vector_type(4))) float f32x4;    // MFMA C/D frag
typedef __attribute__((ext_vector_type(4))) u16   u16x4;

__device__ __forceinline__ u16 f2bf(float f) {              // RNE float->bf16
    u32 u = __float_as_uint(f);
    u32 r = (u + 0x7FFFu + ((u >> 16) & 1u)) >> 16;
    return (u16)r;
}
__device__ __forceinline__ float bf2f(u16 h) {
    return __uint_as_float(((u32)h) << 16);
}
// pack two f32 -> (bf16_b << 16) | bf16_a, RNE, PURE C++ (no inline asm!).
// v_exp_f32 is TRANS-pipe; its result must not be consumed by inline asm — the
// hazard recognizer cannot protect asm readers (R6/R8/R11/R12 failures; R13 proof).
__device__ __forceinline__ u32 pack2bf(float a, float b) {
    u32 ua = __float_as_uint(a), ub = __float_as_uint(b);
    u32 ra = (ua + 0x7FFFu + ((ua >> 16) & 1u)) >> 16;
    u32 rb = (ub + 0x7FFFu + ((ub >> 16) & 1u)) & 0xFFFF0000u;
    return ra | rb;
}
// single v_exp_f32 (TRANS pipe); consumers must be compiler-generated VALU only.
__device__ __forceinline__ float fexp2(float x) {
    return __builtin_amdgcn_exp2f(x);
}

// async global->LDS, 16B per lane. LDS dest is wave-uniform base (HW adds lane*16).
__device__ __forceinline__ void gll16(const u16* g, u16* l) {
    __builtin_amdgcn_global_load_lds(
        (const __attribute__((address_space(1))) u32*)(const void*)g,
        (__attribute__((address_space(3))) u32*)(void*)l, 16, 0, 0);
}

// ---------------- prep: fp32 -> bf16 (hi only) ----------------
__global__ void prep_hi(const float* __restrict__ src, u16* __restrict__ hi, int n4) {
    int i = blockIdx.x * blockDim.x + threadIdx.x;
    if (i >= n4) return;
    f32x4 v = *(const f32x4*)(src + (size_t)i * 4);
    u16x4 h;
#pragma unroll
    for (int j = 0; j < 4; j++) h[j] = f2bf(v[j]);
    *(u16x4*)(hi + (size_t)i * 4) = h;
}

// ---------------- prep: transpose (+ optional hi/lo split) weights -> Wt[N][K] -------
template<int WLO>
__global__ __launch_bounds__(256) void prep_wt(
    const float* __restrict__ Wq, const float* __restrict__ Wk, const float* __restrict__ Wv,
    u16* __restrict__ Whi, u16* __restrict__ Wlo, int K) {
    __shared__ float tile[32][33];
    int k0 = blockIdx.y * 32, n0 = blockIdx.x * 32;
    int tx = threadIdx.x & 31, ty = threadIdx.x >> 5;   // ty in 0..7
#pragma unroll
    for (int i = 0; i < 4; i++) {
        int kk = k0 + ty + i * 8;
        int n  = n0 + tx;
        float v;
        if (n < 1024)      v = Wq[(size_t)kk * 1024 + n];
        else if (n < 1280) v = Wk[(size_t)kk * 256 + (n - 1024)];
        else               v = Wv[(size_t)kk * 256 + (n - 1280)];
        tile[ty + i * 8][tx] = v;
    }
    __syncthreads();
#pragma unroll
    for (int i = 0; i < 4; i++) {
        int nn = n0 + ty + i * 8;      // output row (n)
        int kk = k0 + tx;              // output col (k)
        float v = tile[tx][ty + i * 8];
        u16 hh = f2bf(v);
        Whi[(size_t)nn * K + kk] = hh;
        if (WLO) Wlo[(size_t)nn * K + kk] = f2bf(v - bf2f(hh));
    }
}

__global__ void prep_bias(const float* __restrict__ bq, const float* __restrict__ bk,
                          const float* __restrict__ bv, float* __restrict__ out) {
    int i = blockIdx.x * blockDim.x + threadIdx.x;
    if (i >= 1536) return;
    out[i] = (i < 1024) ? bq[i] : ((i < 1280) ? bk[i - 1024] : bv[i - 1280]);
}

// ---------------- GEMM, 2-phase pipelined staging + chunk-XOR LDS swizzle -------------
// C[M][N] = A @ B^T (+ hi/lo split terms if TERMS==3) + bias.  Bt[N][K].
// Tile 128 x BN, 4 waves (2x2), each wave 64 x BN/2.  16x16x32 MFMA.
// MODE 0: write C fp32. MODE 1: fused QKV epilogue -> Qb(*0.125*log2e), Kb, Vb bf16.
template<int TERMS, int MODE, int BN>
__global__ __launch_bounds__(256) void gemm_2ph(
    const u16* __restrict__ Ahi, const u16* __restrict__ Alo,
    const u16* __restrict__ Bhi, const u16* __restrict__ Blo,
    const float* __restrict__ bias, float* __restrict__ C,
    u16* __restrict__ Qb, u16* __restrict__ Kb, u16* __restrict__ Vb,
    int M, int N, int K) {
    constexpr int NL = (TERMS == 3) ? 2 : 1;
    constexpr int NSUB = BN / 32;                       // 16-col subtiles per wave
    __shared__ __align__(16) u16 sA[2][NL][128 * 32];
    __shared__ __align__(16) u16 sB[2][NL][BN * 32];
    int tid = threadIdx.x;
    int lane = tid & 63;
    int wv = tid >> 6;
    int m0 = blockIdx.y * 128, n0 = blockIdx.x * BN;
    int wm = (wv >> 1) * 64, wn = (wv & 1) * (BN / 2);
    int lr = lane & 15, lg = lane >> 4;

    f32x4 acc[4][NSUB];
#pragma unroll
    for (int a = 0; a < 4; a++)
#pragma unroll
        for (int b = 0; b < NSUB; b++) acc[a][b] = (f32x4){0.f, 0.f, 0.f, 0.f};

    // staging geometry: waves cover rows 0..63 (A also +64); 4 chunks of 16B per row
    int rl = wv * 16 + (lane >> 2);
    int jl = (((lane & 3) ^ ((rl >> 1) & 3)) * 8);     // pre-swizzled source chunk
    size_t aoff = (size_t)(m0 + rl) * K + jl;
    size_t boff = (size_t)(n0 + rl) * K + jl;
    size_t rstep = (size_t)64 * K;

    auto STAGE = [&](int buf, int k0) {
#pragma unroll
        for (int lv = 0; lv < NL; lv++) {
            const u16* As = (lv == 0) ? Ahi : Alo;
            const u16* Bs = (lv == 0) ? Bhi : Blo;
            u16* dA = &sA[buf][lv][0] + wv * 512;
            u16* dB = &sB[buf][lv][0] + wv * 512;
            gll16(As + aoff + k0,         dA);
            gll16(As + aoff + rstep + k0, dA + 2048);
            gll16(Bs + boff + k0,         dB);
            if (BN == 128) gll16(Bs + boff + rstep + k0, dB + 2048);
        }
    };
    constexpr int LPS = NL * (3 + (BN == 128 ? 1 : 0));   // loads per stage per wave

    STAGE(0, 0);
    int nit = K >> 5;
    for (int it = 0; it < nit; ++it) {
        int cur = it & 1;
        if (it + 1 < nit) {
            STAGE(cur ^ 1, (it + 1) * 32);             // next tile in flight during compute
            asm volatile("s_waitcnt vmcnt(%0)" :: "n"(LPS) : "memory");
        } else {
            asm volatile("s_waitcnt vmcnt(0)" ::: "memory");
        }
        __builtin_amdgcn_s_barrier();
        asm volatile("" ::: "memory");

        bf16x8 af[NL][4], bfr[NL][NSUB];
#pragma unroll
        for (int ms = 0; ms < 4; ms++) {
            int row = wm + ms * 16 + lr;
            int off = row * 32 + (lg ^ ((row >> 1) & 3)) * 8;
#pragma unroll
            for (int lv = 0; lv < NL; lv++) af[lv][ms] = *(const bf16x8*)&sA[cur][lv][off];
        }
#pragma unroll
        for (int ns = 0; ns < NSUB; ns++) {
            int row = wn + ns * 16 + lr;
            int off = row * 32 + (lg ^ ((row >> 1) & 3)) * 8;
#pragma unroll
            for (int lv = 0; lv < NL; lv++) bfr[lv][ns] = *(const bf16x8*)&sB[cur][lv][off];
        }
#pragma unroll
        for (int ms = 0; ms < 4; ms++)
#pragma unroll
            for (int ns = 0; ns < NSUB; ns++) {
                f32x4 c = acc[ms][ns];
                c = __builtin_amdgcn_mfma_f32_16x16x32_bf16(af[0][ms], bfr[0][ns], c, 0, 0, 0);
                if constexpr (TERMS == 3) {
                    c = __builtin_amdgcn_mfma_f32_16x16x32_bf16(af[0][ms], bfr[1][ns], c, 0, 0, 0);
                    c = __builtin_amdgcn_mfma_f32_16x16x32_bf16(af[1][ms], bfr[0][ns], c, 0, 0, 0);
                }
                acc[ms][ns] = c;
            }
        __builtin_amdgcn_s_barrier();   // all reads of cur done before it is restaged
    }

    int rq = lg * 4;
#pragma unroll
    for (int ns = 0; ns < NSUB; ns++) {
        int n = n0 + wn + ns * 16 + lr;
        float bvv = bias[n];
#pragma unroll
        for (int ms = 0; ms < 4; ms++) {
            int mbase = m0 + wm + ms * 16 + rq;
#pragma unroll
            for (int r = 0; r < 4; r++) {
                float val = acc[ms][ns][r] + bvv;
                int m = mbase + r;
                if (MODE == 0) {
                    C[(size_t)m * N + n] = val;
                } else {
                    if (n < 1024)      Qb[(size_t)m * 1024 + n] = f2bf(val * 0.1803368801f);
                    else if (n < 1280) Kb[(size_t)m * 256 + (n - 1024)] = f2bf(val);
                    else               Vb[(size_t)m * 256 + (n - 1280)] = f2bf(val);
                }
            }
        }
    }
}

// ---------------- prep: Vb bf16 -> V^T per (b,g), key-PERMUTED within 64-blocks -------
// position p within a 64-token block holds token ti = ((p&1)<<4) | ((p>>1)&15) | (p&32)
// (so positions 2i/2i+1 = tokens i/16+i) matching the P-pack layout in attn.
__global__ __launch_bounds__(256) void prep_vt(const u16* __restrict__ Vb,
                                               u16* __restrict__ Vtp) {
    int blk = blockIdx.x;                 // 2*4*32
    int tk = blk & 31, gg = (blk >> 5) & 3, bb = blk >> 7;
    int tok0 = tk * 64;
    __shared__ u16 lt[64][72];
    int t = threadIdx.x;
#pragma unroll
    for (int i = 0; i < 16; i++) {
        int idx = t + i * 256;
        int ti = idx >> 6, dh = idx & 63;
        lt[dh][ti] = Vb[(size_t)(bb * 2048 + tok0 + ti) * 256 + gg * 64 + dh];
    }
    __syncthreads();
#pragma unroll
    for (int i = 0; i < 16; i++) {
        int idx = t + i * 256;
        int dh = idx >> 6, p = idx & 63;
        int ti = ((p & 1) << 4) | ((p >> 1) & 15) | (p & 32);
        Vtp[(size_t)((bb * 4 + gg) * 64 + dh) * 2048 + tok0 + p] = lt[dh][ti];
    }
}

// ---------------- flash attention (R3-proven structure, 73.5us): ----------------------
// 4 waves x 32 q-rows = 128 rows/block, 512 blocks; each wave walks ALL 2048 keys.
// K/V staged in LDS via global_load_lds (shared by the 4 waves, amortized 4x),
// double-buffered, counted vmcnt(4), barrier-synced. 16B-chunk XOR swizzle via
// pre-swizzled global source + swizzled reads (rule 21). No-max exp2 softmax
// (Q pre-scaled by 0.125*log2e), deferred denominator; writes O as hi/lo bf16.
// Changes vs R3 original (both R13-proven safe): exp2f -> builtin, cvtpk -> pack2bf.
__global__ __launch_bounds__(256) void attn_kernel(
    const u16* __restrict__ Qb, const u16* __restrict__ Kb,
    const u16* __restrict__ Vtp, u16* __restrict__ Ohi, u16* __restrict__ Olo) {
    __shared__ __align__(16) u16 sK[2][4096];
    __shared__ __align__(16) u16 sV[2][4096];
    __shared__ __align__(16) u16 sP[4][32 * 72];

    const int tid = threadIdx.x;
    const int wv = tid >> 6, lane = tid & 63;
    const int lr = lane & 15, lg = lane >> 4;

    const int bid = blockIdx.x;
    const int tc = bid & 15;
    const int h  = (bid >> 4) & 15;
    const int b  = bid >> 8;
    const int g  = h >> 2;
    const int tok0 = tc * 128 + wv * 32;

    // Q A-fragments: 2 m-tiles x 2 k-steps
    bf16x8 qf[2][2];
#pragma unroll
    for (int mm = 0; mm < 2; mm++) {
        const u16* qrow = Qb + (size_t)(b * 2048 + tok0 + mm * 16 + lr) * 1024 + h * 64 + lg * 8;
        qf[mm][0] = *(const bf16x8*)(qrow);
        qf[mm][1] = *(const bf16x8*)(qrow + 32);
    }

    // staging: wave covers rows wv*16..+15 (2 issues of 8 rows), swizzled source chunk
    const int srow = wv * 16 + (lane >> 3);
    const int sjj  = (lane & 7) ^ (srow & 7);
    const u16* kgb = Kb  + (size_t)(b * 2048 + srow) * 256 + g * 64 + sjj * 8;
    const u16* vgb = Vtp + (size_t)((b * 4 + g) * 64 + srow) * 2048 + sjj * 8;
    u16* kds = &sK[0][0] + wv * 1024;
    u16* vds = &sV[0][0] + wv * 1024;

    f32x4 o_[2][4];
    float ls[2][4];
#pragma unroll
    for (int mm = 0; mm < 2; mm++)
#pragma unroll
        for (int r = 0; r < 4; r++) { o_[mm][r] = (f32x4){0.f, 0.f, 0.f, 0.f}; ls[mm][r] = 0.f; }

    // prologue: stage tile 0 into buffer 0
    gll16(kgb,         kds);
    gll16(kgb + 2048,  kds + 512);
    gll16(vgb,         vds);
    gll16(vgb + 16384, vds + 512);

    for (int it = 0; it < 32; ++it) {
        const int cur = it & 1;
        if (it < 31) {
            const u16* kp = kgb + (size_t)(it + 1) * 16384;
            const u16* vp = vgb + (size_t)(it + 1) * 64;
            u16* kd = kds + (cur ^ 1) * 4096;
            u16* vd = vds + (cur ^ 1) * 4096;
            gll16(kp,         kd);
            gll16(kp + 2048,  kd + 512);
            gll16(vp,         vd);
            gll16(vp + 16384, vd + 512);
            asm volatile("s_waitcnt vmcnt(4)" ::: "memory");   // cur landed, next 4 in flight
        } else {
            asm volatile("s_waitcnt vmcnt(0)" ::: "memory");
        }
        __builtin_amdgcn_s_barrier();

        const u16* kt = &sK[cur][0];
        const u16* vt = &sV[cur][0];

        // K fragments (shared across m-tiles)
        bf16x8 kf0[4], kf1[4];
#pragma unroll
        for (int t = 0; t < 4; t++) {
            int row = t * 16 + lr;
            kf0[t] = *(const bf16x8*)(kt + (row * 8 + (lg ^ (row & 7))) * 8);
            kf1[t] = *(const bf16x8*)(kt + (row * 8 + ((4 + lg) ^ (row & 7))) * 8);
        }
        // S = Q @ K^T (exp2 domain)
        f32x4 s[2][4];
#pragma unroll
        for (int mm = 0; mm < 2; mm++)
#pragma unroll
            for (int t = 0; t < 4; t++) {
                f32x4 sc = (f32x4){0.f, 0.f, 0.f, 0.f};
                sc = __builtin_amdgcn_mfma_f32_16x16x32_bf16(qf[mm][0], kf0[t], sc, 0, 0, 0);
                sc = __builtin_amdgcn_mfma_f32_16x16x32_bf16(qf[mm][1], kf1[t], sc, 0, 0, 0);
                s[mm][t] = sc;
            }

        // P = exp2(S); accumulate denominator per-lane; pack pairs -> LDS
        u16* sPw = &sP[wv][0];
#pragma unroll
        for (int mm = 0; mm < 2; mm++)
#pragma unroll
            for (int r = 0; r < 4; r++) {
                float p0 = fexp2(s[mm][0][r]);
                float p1 = fexp2(s[mm][1][r]);
                float p2 = fexp2(s[mm][2][r]);
                float p3 = fexp2(s[mm][3][r]);
                ls[mm][r] += (p0 + p1) + (p2 + p3);
                u32 w0 = pack2bf(p0, p1);        // positions 2lr,2lr+1 = keys lr,16+lr
                u32 w1 = pack2bf(p2, p3);        // positions 32+2lr,.. = keys 32+lr,48+lr
                int rowo = (mm * 16 + lg * 4 + r) * 72;
                *(u32*)(sPw + rowo + lr * 2)      = w0;
                *(u32*)(sPw + rowo + 32 + lr * 2) = w1;
            }
        asm volatile("s_waitcnt lgkmcnt(0)" ::: "memory");
        __builtin_amdgcn_sched_barrier(0);

        // O += P @ V  (V tile is key-permuted to match P's packed positions)
#pragma unroll
        for (int ks = 0; ks < 2; ks++) {
            bf16x8 vf[4];
#pragma unroll
            for (int n = 0; n < 4; n++) {
                int row = n * 16 + lr;
                vf[n] = *(const bf16x8*)(vt + (row * 8 + ((ks * 4 + lg) ^ (row & 7))) * 8);
            }
#pragma unroll
            for (int mm = 0; mm < 2; mm++) {
                bf16x8 pa = *(const bf16x8*)(sPw + (mm * 16 + lr) * 72 + ks * 32 + lg * 8);
#pragma unroll
                for (int n = 0; n < 4; n++)
                    o_[mm][n] = __builtin_amdgcn_mfma_f32_16x16x32_bf16(pa, vf[n], o_[mm][n], 0, 0, 0);
            }
        }
        __builtin_amdgcn_s_barrier();   // all reads of cur done before restage
    }

    // deferred denominator reduce + normalize + hi/lo split write
#pragma unroll
    for (int mm = 0; mm < 2; mm++)
#pragma unroll
        for (int r = 0; r < 4; r++) {
            float l = ls[mm][r];
#pragma unroll
            for (int off = 1; off < 16; off <<= 1) l += __shfl_xor(l, off, 64);
            float inv = 1.f / l;
            int row = b * 2048 + tok0 + mm * 16 + lg * 4 + r;
#pragma unroll
            for (int n = 0; n < 4; n++) {
                float val = o_[mm][n][r] * inv;
                u16 hh = f2bf(val);
                size_t idx = (size_t)row * 1024 + h * 64 + n * 16 + lr;
                Ohi[idx] = hh;
                Olo[idx] = f2bf(val - bf2f(hh));
            }
        }
}

// ---------------- launch ----------------
extern "C" void kernel_launch(void* const* d_in, const int* in_sizes, int n_in,
                              void* d_out, int out_size, void* d_ws, size_t ws_size,
                              hipStream_t stream) {
    const float* x   = (const float*)d_in[0];
    const float* W_q = (const float*)d_in[1];
    const float* b_q = (const float*)d_in[2];
    const float* W_k = (const float*)d_in[3];
    const float* b_k = (const float*)d_in[4];
    const float* W_v = (const float*)d_in[5];
    const float* b_v = (const float*)d_in[6];
    const float* W_o = (const float*)d_in[7];
    const float* b_o = (const float*)d_in[8];
    float* out = (float*)d_out;

    char* ws = (char*)d_ws;
    u16*   xhi   = (u16*)(ws + 0);            //  8 MB  [4096][1024]
    u16*   Wqkvh = (u16*)(ws + 8388608);      //  3 MB  [1536][1024]
    float* bqkv  = (float*)(ws + 11534336);   //  6 KB
    u16*   Qb    = (u16*)(ws + 11540480);     //  8 MB  [4096][1024] (pre-scaled)
    u16*   Kb    = (u16*)(ws + 19929088);     //  2 MB  [4096][256]
    u16*   Vb    = (u16*)(ws + 22026240);     //  2 MB  [4096][256]
    u16*   Vtp   = (u16*)(ws + 24123392);     //  2 MB  [8][64][2048] key-permuted
    u16*   Woh   = (u16*)(ws + 26220544);     //  2 MB  [1024][1024]
    u16*   Wol   = (u16*)(ws + 28317696);     //  2 MB
    u16*   Ahi   = (u16*)(ws + 30414848);     //  8 MB  attn-out hi
    u16*   Alo   = (u16*)(ws + 38803456);     //  8 MB  attn-out lo (ends 47,192,064)

    prep_hi<<<4096, 256, 0, stream>>>(x, xhi, 4096 * 1024 / 4);
    prep_wt<0><<<dim3(48, 32), 256, 0, stream>>>(W_q, W_k, W_v, Wqkvh, nullptr, 1024);
    prep_wt<1><<<dim3(32, 32), 256, 0, stream>>>(W_o, W_o, W_o, Woh, Wol, 1024);
    prep_bias<<<6, 256, 0, stream>>>(b_q, b_k, b_v, bqkv);
    gemm_2ph<1, 1, 64><<<dim3(24, 32), 256, 0, stream>>>(xhi, nullptr, Wqkvh, nullptr, bqkv,
                                                         nullptr, Qb, Kb, Vb, 4096, 1536, 1024);
    prep_vt<<<256, 256, 0, stream>>>(Vb, Vtp);
    attn_kernel<<<512, 256, 0, stream>>>(Qb, Kb, Vtp, Ahi, Alo);
    gemm_2ph<3, 0, 64><<<dim3(16, 32), 256, 0, stream>>>(Ahi, Alo, Woh, Wol, b_o, out,
                                                         nullptr, nullptr, nullptr, 4096, 1024, 1024);
}